// Round 8
// baseline (351.695 us; speedup 1.0000x reference)
//
#include <hip/hip_runtime.h>

#define EPS_DIR 1e-15f
#define EPS_W   1e-5f
#define NEAR_MIN 0.05f

// ---------------------------------------------------------------------------
// Specialized kernel for Tm1=127, n=128: 8 lanes/ray, REGISTER-ONLY scatter.
//
// Round-5 post-mortem: the LDS binary search was LDS-bound, not VALU-bound:
// 112 ds_reads/thread at ~4-way bank conflict (lanes of a group sit at
// p ~= 16g -> banks {0,16} mod 32) = 28M conflict cycles (~46us across chip)
// plus ~35us raw LDS occupancy (4 SIMDs share one LDS pipe per CU).
// Fix: no LDS at all. Lane g owns bins [16g,16g+16); its 16 running sums
// and c_hi values live in statically-indexed registers. Sample ranges are
// derived from shfl-shared prefix bits (round-0's verified exact-partition
// scheme: both sides of each boundary compute ceil(fmaf(128,c,-0.5)) from
// the SAME float, so ranges exactly partition [0,128)). Emit is a per-bin
// while loop (divergent, wave pays max samples/bin ~4) writing scalar
// scatter stores that L2 merges (round-0 measured exact 131MB writes).
// ---------------------------------------------------------------------------
__global__ __launch_bounds__(256) void nerf_sample_pdf_127_128(
    const float* __restrict__ rays_o,
    const float* __restrict__ rays_d,
    const float* __restrict__ weights,
    const int*   __restrict__ bound_p,
    float*       __restrict__ out,
    int R)
{
    const int t    = threadIdx.x;
    const int g    = t & 7;            // lane within 8-lane ray group
    const int rloc = t >> 3;           // ray within block (0..31)
    int ray = blockIdx.x * 32 + rloc;
    const bool valid = (ray < R);
    if (!valid) ray = R - 1;           // clamp: loads safe, emits disabled below

    // ---- 16 weights per lane, registers, static indexing ----
    const float* __restrict__ wrow = weights + (size_t)ray * 127;
    const int i0 = g << 4;             // first bin owned by this lane
    float w[16];
#pragma unroll
    for (int k = 0; k < 16; ++k) {
        const int i = i0 + k;
        w[k] = (i < 127) ? (wrow[i] + EPS_W) : 0.0f;   // only g=7,k=15 masked
    }

    float local = w[0];
#pragma unroll
    for (int k = 1; k < 16; ++k) local += w[k];

    // ---- 8-lane xor-butterfly: exclusive prefix + group total ----
    float prefix = 0.0f, val = local;  // prefix==0.0 exactly for g==0
#pragma unroll
    for (int k = 1; k < 8; k <<= 1) {
        const float y = __shfl_xor(val, k, 8);
        if (g & k) prefix += y;
        val += y;                       // ends as group total in every lane
    }
    const float rtot  = __builtin_amdgcn_rcpf(val);
    const float pnext = __shfl_down(prefix, 1, 8);  // lane g+1's prefix (g=7: unused)

    // ---- per-bin normalized cdf upper bounds, in registers ----
    float ch[16];
    {
        float run = prefix;
#pragma unroll
        for (int k = 0; k < 16; ++k) { run += w[k]; ch[k] = run * rtot; }
    }
    const float c_lo0 = prefix * rtot;

    // ---- near/far cube intersection (one wave-inst serves all 8 rays) ----
    const float b = (float)bound_p[0];
    float nearv = -3.4e38f, farv = 3.4e38f;
#pragma unroll
    for (int k = 0; k < 3; ++k) {
        const float o = rays_o[(size_t)ray * 3 + k];
        const float d = rays_d[(size_t)ray * 3 + k] + EPS_DIR;
        const float r = __builtin_amdgcn_rcpf(d);
        const float t0 = (-b - o) * r;
        const float t1 = ( b - o) * r;
        nearv = fmaxf(nearv, fminf(t0, t1));
        farv  = fminf(farv,  fmaxf(t0, t1));
    }
    nearv = fmaxf(nearv, NEAR_MIN);
    const float scale = (farv - nearv) * (1.0f / 127.0f);

    // ---- owned sample range [j0, jend): identical expression both sides of
    //      each lane boundary, fed the same float -> exact partition ----
    int j0 = (int)ceilf(fmaf(128.0f, c_lo0, -0.5f));
    if (j0 < 0) j0 = 0;
    int jend;
    if (g == 7) {
        jend = 128;                    // absorb u~1 vs rcp rounding
    } else {
        jend = (int)ceilf(fmaf(128.0f, pnext * rtot, -0.5f));
        if (jend > 128) jend = 128;
    }
    if (!valid) { j0 = 0; jend = 0; }  // tail block: no emits

    float* __restrict__ orow = out + (size_t)ray * 128;
    const float inv_n = 1.0f / 128.0f; // 2^-7: u arithmetic below is exact

    int   j    = j0;
    float u    = fmaf((float)j, inv_n, 0.5f * inv_n);
    float c_lo = c_lo0;
#pragma unroll
    for (int k = 0; k < 16; ++k) {
        const float c_hi = ch[k];
        const float dnm  = c_hi - c_lo;
        const float rd   = (dnm < EPS_W) ? 1.0f : __builtin_amdgcn_rcpf(dnm);
        const float zb   = fmaf((float)(i0 + k), scale, nearv);
        if (k < 15) {
            // bin k holds u while cdf[k] <= u < cdf[k+1]  (searchsorted-right)
            while (j < jend && u < c_hi) {
                orow[j] = fmaf((u - c_lo) * rd, scale, zb);
                ++j; u += inv_n;
            }
        } else {
            // last owned bin: force-emit remainder (boundary bit-noise only)
            while (j < jend) {
                orow[j] = fmaf((u - c_lo) * rd, scale, zb);
                ++j; u += inv_n;
            }
        }
        c_lo = c_hi;
    }
}

// ---------------------------------------------------------------------------
// Generic fallback (round-3 kernel, verified correct): wave-per-ray gather.
// Used only if the shape is not (Tm1=127, n=128).
// ---------------------------------------------------------------------------
__global__ __launch_bounds__(256) void nerf_sample_pdf_generic(
    const float* __restrict__ rays_o,
    const float* __restrict__ rays_d,
    const float* __restrict__ weights,
    const int*   __restrict__ bound_p,
    float*       __restrict__ out,
    int R, int Tm1, int n)
{
    const int lane = threadIdx.x & 63;
    const int wid  = threadIdx.x >> 6;
    int ray = blockIdx.x * 4 + wid;
    const bool valid = (ray < R);
    if (!valid) ray = R - 1;

    __shared__ float cdf_s[4][132];
    float* __restrict__ cdf = cdf_s[wid];

    const float* __restrict__ wrow = weights + (size_t)ray * Tm1;
    const int i0 = 2 * lane, i1 = 2 * lane + 1;
    float w0 = (i0 < Tm1) ? (wrow[i0] + EPS_W) : 0.0f;
    float w1 = (i1 < Tm1) ? (wrow[i1] + EPS_W) : 0.0f;

    float S = w0 + w1;
#pragma unroll
    for (int off = 1; off < 64; off <<= 1) {
        float y = __shfl_up(S, off, 64);
        if (lane >= off) S += y;
    }
    const float total = __shfl(S, 63, 64);
    const float rinv  = __builtin_amdgcn_rcpf(total);
    float prevS = __shfl_up(S, 1, 64);
    if (lane == 0) prevS = 0.0f;

    cdf[i0] = prevS * rinv;
    cdf[i1] = (prevS + w0) * rinv;
    __syncthreads();

    const float b = (float)bound_p[0];
    float nearv = -3.4e38f, farv = 3.4e38f;
#pragma unroll
    for (int k = 0; k < 3; ++k) {
        float o = rays_o[(size_t)ray * 3 + k];
        float d = rays_d[(size_t)ray * 3 + k] + EPS_DIR;
        float r = __builtin_amdgcn_rcpf(d);
        float t0 = (-b - o) * r;
        float t1 = ( b - o) * r;
        nearv = fmaxf(nearv, fminf(t0, t1));
        farv  = fminf(farv,  fmaxf(t0, t1));
    }
    nearv = fmaxf(nearv, NEAR_MIN);
    const float scale = (farv - nearv) * __builtin_amdgcn_rcpf((float)Tm1);
    const float inv_n = 1.0f / (float)n;

    float* __restrict__ orow = out + (size_t)ray * n;

    for (int base = 0; base < n; base += 128) {
        const int j = base + 2 * lane;
        if (j >= n) break;
        const float u0 = ((float)j + 0.5f) * inv_n;
        const float u1 = u0 + inv_n;

        int   p0 = 0,   p1 = 0;
        float v0 = 0.f, v1 = 0.f;
#pragma unroll
        for (int step = 64; step >= 1; step >>= 1) {
            if (p0 + step <= Tm1) {
                const float c0 = cdf[p0 + step];
                if (c0 <= u0) { p0 += step; v0 = c0; }
            }
            if (p1 + step <= Tm1) {
                const float c1 = cdf[p1 + step];
                if (c1 <= u1) { p1 += step; v1 = c1; }
            }
        }
        const int a0 = (p0 < Tm1) ? p0 + 1 : Tm1;
        const int a1 = (p1 < Tm1) ? p1 + 1 : Tm1;
        const float h0 = cdf[a0];
        const float h1 = cdf[a1];
        const float d0 = h0 - v0;
        const float d1 = h1 - v1;
        const float t0 = (u0 - v0) * ((d0 < EPS_W) ? 1.0f : __builtin_amdgcn_rcpf(d0));
        const float t1 = (u1 - v1) * ((d1 < EPS_W) ? 1.0f : __builtin_amdgcn_rcpf(d1));
        const float z0 = fmaf(t0, (float)(a0 - p0) * scale, fmaf((float)p0, scale, nearv));
        const float z1 = fmaf(t1, (float)(a1 - p1) * scale, fmaf((float)p1, scale, nearv));

        if (valid) {
            if (j + 1 < n) {
                *reinterpret_cast<float2*>(orow + j) = make_float2(z0, z1);
            } else {
                orow[j] = z0;
            }
        }
    }
}

extern "C" void kernel_launch(void* const* d_in, const int* in_sizes, int n_in,
                              void* d_out, int out_size, void* d_ws, size_t ws_size,
                              hipStream_t stream) {
    const float* rays_o  = (const float*)d_in[0];
    const float* rays_d  = (const float*)d_in[1];
    const float* weights = (const float*)d_in[2];
    const int*   bound_p = (const int*)d_in[3];
    float*       out     = (float*)d_out;

    const int R   = in_sizes[0] / 3;       // 262144 rays
    const int Tm1 = in_sizes[2] / R;       // 127 weights per ray
    const int n   = out_size / R;          // 128 samples per ray

    if (Tm1 == 127 && n == 128) {
        dim3 grid((R + 31) / 32), block(256);   // 32 rays/block, 8 lanes/ray
        nerf_sample_pdf_127_128<<<grid, block, 0, stream>>>(
            rays_o, rays_d, weights, bound_p, out, R);
    } else {
        dim3 grid((R + 3) / 4), block(256);
        nerf_sample_pdf_generic<<<grid, block, 0, stream>>>(
            rays_o, rays_d, weights, bound_p, out, R, Tm1, n);
    }
}

// Round 9
// 276.891 us; speedup vs baseline: 1.2702x; 1.2702x over previous
//
#include <hip/hip_runtime.h>

#define EPS_DIR 1e-15f
#define EPS_W   1e-5f
#define NEAR_MIN 0.05f

// ---------------------------------------------------------------------------
// Tm1=127, n=128 specialized: 8 lanes/ray, coalesced-staged LDS CDF gather.
//
// Round-8 post-mortem: register-only scatter was VMEM-address-issue bound
// (all counters idle, 190us): 16 scattered weight loads (64 lines/inst) +
// ~1024 single-line store txns per wave. Round 5 (94.9us, best) paid
// ~46us bank conflicts + ~35us LDS pipe + ~55us scattered-load TA.
// This round fixes all three while keeping round-5's coalesced stores:
//  1. weights staged per-wave into LDS with fully-coalesced loads
//     (idx=64k+lane over the 8-row contiguous span), lanes then pull
//     their 16 weights from LDS (cheap) instead of 64-line global insts.
//  2. cdf tables at stride 133 (=5 mod 32) + quad assignment j=32i+4g:
//     concurrent search positions spaced 4g -> distinct banks in a group
//     (round 5's 16g clustering was the 28M-cycle conflict source);
//     early search steps are same-address broadcasts (free).
//  3. one 7-step search per quad leader + incremental advance for the
//     other 3 samples: ~48 cdf reads/thread vs 112.
// Stores: float4 at 32i+4g -> each group writes a contiguous 128B chunk
// per store inst (16 lines/inst/wave, coalesced).
// One __syncthreads after staging (also a compiler fence for the raw->cdf
// buffer reuse); everything after is same-wave in-order LDS.
// ---------------------------------------------------------------------------
__global__ __launch_bounds__(256) void nerf_sample_pdf_127_128(
    const float* __restrict__ rays_o,
    const float* __restrict__ rays_d,
    const float* __restrict__ weights,
    const int*   __restrict__ bound_p,
    float*       __restrict__ out,
    int R)
{
    const int t    = threadIdx.x;
    const int lane = t & 63;
    const int wv   = t >> 6;           // wave in block (0..3)
    const int g    = t & 7;            // lane within 8-lane ray group
    const int rw   = lane >> 3;        // ray within wave (0..7)
    const int rloc = t >> 3;           // ray within block (0..31)
    const int ray  = blockIdx.x * 32 + rloc;
    const bool valid = (ray < R);
    const int rayc = valid ? ray : (R - 1);   // clamped for ray_o/d loads

    // Per-wave buffer: raw weights [0,1016) then cdf tables (8 x stride 133,
    // max index 133*7+128 = 1059). Phases separated by __syncthreads.
    __shared__ float buf_s[4][1072];   // 17152 B/block
    float* __restrict__ wbuf = buf_s[wv];

    // ---- phase A: stage this wave's 8 weight rows, fully coalesced ----
    {
        const int ray0 = blockIdx.x * 32 + wv * 8;
        const size_t gbase = (size_t)ray0 * 127;
        const size_t total = (size_t)R * 127;
#pragma unroll
        for (int k = 0; k < 16; ++k) {
            const int idx = 64 * k + lane;
            if (idx < 1016) {
                const size_t gi = gbase + (size_t)idx;
                wbuf[idx] = (gi < total) ? weights[gi] : 0.0f;
            }
        }
    }

    // ---- phase B: lane pulls its 16 weights (row rw, cols 16g..16g+15) ----
    const int i0 = g << 4;
    float w[16];
#pragma unroll
    for (int k = 0; k < 16; ++k) {
        const float rv = wbuf[127 * rw + i0 + k];   // max 1016 < 1072
        w[k] = (i0 + k < 127) ? rv + EPS_W : 0.0f;  // mask the phantom 128th
    }

    float local = w[0];
#pragma unroll
    for (int k = 1; k < 16; ++k) local += w[k];

    // ---- 8-lane xor-butterfly: exclusive prefix + total ----
    float prefix = 0.0f, val = local;
#pragma unroll
    for (int k = 1; k < 8; k <<= 1) {
        const float y = __shfl_xor(val, k, 8);
        if (g & k) prefix += y;
        val += y;                       // ends as group total
    }
    const float rtot = __builtin_amdgcn_rcpf(val);

    // Fence: all raw reads complete before cdf writes reuse the buffer
    // (also the block-wide LDS visibility barrier).
    __syncthreads();

    // ---- phase C: build per-ray cdf at stride 133 (single-writer/entry) ----
    float* __restrict__ cdf = wbuf + 133 * rw;
    if (g == 0) cdf[0] = 0.0f;
    {
        float run = prefix;
#pragma unroll
        for (int k = 0; k < 16; ++k) {
            run += w[k];
            cdf[i0 + k + 1] = run * rtot;   // g=7 writes entry 128 (dup of 127)
        }
    }

    // ---- near/far cube intersection (8-lane redundant) ----
    const float b = (float)bound_p[0];
    float nearv = -3.4e38f, farv = 3.4e38f;
#pragma unroll
    for (int k = 0; k < 3; ++k) {
        const float o = rays_o[(size_t)rayc * 3 + k];
        const float d = rays_d[(size_t)rayc * 3 + k] + EPS_DIR;
        const float r = __builtin_amdgcn_rcpf(d);
        const float t0 = (-b - o) * r;
        const float t1 = ( b - o) * r;
        nearv = fmaxf(nearv, fminf(t0, t1));
        farv  = fminf(farv,  fmaxf(t0, t1));
    }
    nearv = fmaxf(nearv, NEAR_MIN);
    const float scale = (farv - nearv) * (1.0f / 127.0f);

    // ---- phase D: 4 quads of 4 samples, j = 32i + 4g + s ----
    // searchsorted(side='right'): p = largest e with cdf[e] <= u.
    // Leader: 7-step binary lift (step-64 read is a per-table broadcast).
    // Followers: advance while cdf[p+1] <= u (exact same semantics).
    float* __restrict__ orow = out + (size_t)ray * 128;
    const float inv_n = 1.0f / 128.0f;     // u values exact dyadics

#pragma unroll
    for (int i = 0; i < 4; ++i) {
        const int jb = 32 * i + 4 * g;
        float u = ((float)jb + 0.5f) * inv_n;
        int   p = 0;
        float v = 0.0f;
#pragma unroll
        for (int step = 64; step >= 1; step >>= 1) {
            const float c = cdf[p + step];          // p+step <= 127
            if (c <= u) { p += step; v = c; }
        }
        float h = cdf[p + 1];                       // entry 128 exists (dup)
        float z0, z1, z2, z3;
#pragma unroll
        for (int s = 0; s < 4; ++s) {
            while (h <= u && p < 127) { ++p; v = h; h = cdf[p + 1]; }
            const float dnm = h - v;
            const float rd  = (dnm < EPS_W) ? 1.0f : __builtin_amdgcn_rcpf(dnm);
            const float z   = fmaf((float)p + (u - v) * rd, scale, nearv);
            if      (s == 0) z0 = z;
            else if (s == 1) z1 = z;
            else if (s == 2) z2 = z;
            else             z3 = z;
            u += inv_n;
        }
        if (valid) {
            *reinterpret_cast<float4*>(orow + jb) = make_float4(z0, z1, z2, z3);
        }
    }
}

// ---------------------------------------------------------------------------
// Generic fallback (round-3 kernel, verified correct): wave-per-ray gather.
// Used only if the shape is not (Tm1=127, n=128).
// ---------------------------------------------------------------------------
__global__ __launch_bounds__(256) void nerf_sample_pdf_generic(
    const float* __restrict__ rays_o,
    const float* __restrict__ rays_d,
    const float* __restrict__ weights,
    const int*   __restrict__ bound_p,
    float*       __restrict__ out,
    int R, int Tm1, int n)
{
    const int lane = threadIdx.x & 63;
    const int wid  = threadIdx.x >> 6;
    int ray = blockIdx.x * 4 + wid;
    const bool valid = (ray < R);
    if (!valid) ray = R - 1;

    __shared__ float cdf_s[4][132];
    float* __restrict__ cdf = cdf_s[wid];

    const float* __restrict__ wrow = weights + (size_t)ray * Tm1;
    const int i0 = 2 * lane, i1 = 2 * lane + 1;
    float w0 = (i0 < Tm1) ? (wrow[i0] + EPS_W) : 0.0f;
    float w1 = (i1 < Tm1) ? (wrow[i1] + EPS_W) : 0.0f;

    float S = w0 + w1;
#pragma unroll
    for (int off = 1; off < 64; off <<= 1) {
        float y = __shfl_up(S, off, 64);
        if (lane >= off) S += y;
    }
    const float total = __shfl(S, 63, 64);
    const float rinv  = __builtin_amdgcn_rcpf(total);
    float prevS = __shfl_up(S, 1, 64);
    if (lane == 0) prevS = 0.0f;

    cdf[i0] = prevS * rinv;
    cdf[i1] = (prevS + w0) * rinv;
    __syncthreads();

    const float b = (float)bound_p[0];
    float nearv = -3.4e38f, farv = 3.4e38f;
#pragma unroll
    for (int k = 0; k < 3; ++k) {
        float o = rays_o[(size_t)ray * 3 + k];
        float d = rays_d[(size_t)ray * 3 + k] + EPS_DIR;
        float r = __builtin_amdgcn_rcpf(d);
        float t0 = (-b - o) * r;
        float t1 = ( b - o) * r;
        nearv = fmaxf(nearv, fminf(t0, t1));
        farv  = fminf(farv,  fmaxf(t0, t1));
    }
    nearv = fmaxf(nearv, NEAR_MIN);
    const float scale = (farv - nearv) * __builtin_amdgcn_rcpf((float)Tm1);
    const float inv_n = 1.0f / (float)n;

    float* __restrict__ orow = out + (size_t)ray * n;

    for (int base = 0; base < n; base += 128) {
        const int j = base + 2 * lane;
        if (j >= n) break;
        const float u0 = ((float)j + 0.5f) * inv_n;
        const float u1 = u0 + inv_n;

        int   p0 = 0,   p1 = 0;
        float v0 = 0.f, v1 = 0.f;
#pragma unroll
        for (int step = 64; step >= 1; step >>= 1) {
            if (p0 + step <= Tm1) {
                const float c0 = cdf[p0 + step];
                if (c0 <= u0) { p0 += step; v0 = c0; }
            }
            if (p1 + step <= Tm1) {
                const float c1 = cdf[p1 + step];
                if (c1 <= u1) { p1 += step; v1 = c1; }
            }
        }
        const int a0 = (p0 < Tm1) ? p0 + 1 : Tm1;
        const int a1 = (p1 < Tm1) ? p1 + 1 : Tm1;
        const float h0 = cdf[a0];
        const float h1 = cdf[a1];
        const float d0 = h0 - v0;
        const float d1 = h1 - v1;
        const float t0 = (u0 - v0) * ((d0 < EPS_W) ? 1.0f : __builtin_amdgcn_rcpf(d0));
        const float t1 = (u1 - v1) * ((d1 < EPS_W) ? 1.0f : __builtin_amdgcn_rcpf(d1));
        const float z0 = fmaf(t0, (float)(a0 - p0) * scale, fmaf((float)p0, scale, nearv));
        const float z1 = fmaf(t1, (float)(a1 - p1) * scale, fmaf((float)p1, scale, nearv));

        if (valid) {
            if (j + 1 < n) {
                *reinterpret_cast<float2*>(orow + j) = make_float2(z0, z1);
            } else {
                orow[j] = z0;
            }
        }
    }
}

extern "C" void kernel_launch(void* const* d_in, const int* in_sizes, int n_in,
                              void* d_out, int out_size, void* d_ws, size_t ws_size,
                              hipStream_t stream) {
    const float* rays_o  = (const float*)d_in[0];
    const float* rays_d  = (const float*)d_in[1];
    const float* weights = (const float*)d_in[2];
    const int*   bound_p = (const int*)d_in[3];
    float*       out     = (float*)d_out;

    const int R   = in_sizes[0] / 3;       // 262144 rays
    const int Tm1 = in_sizes[2] / R;       // 127 weights per ray
    const int n   = out_size / R;          // 128 samples per ray

    if (Tm1 == 127 && n == 128) {
        dim3 grid((R + 31) / 32), block(256);   // 32 rays/block, 8 lanes/ray
        nerf_sample_pdf_127_128<<<grid, block, 0, stream>>>(
            rays_o, rays_d, weights, bound_p, out, R);
    } else {
        dim3 grid((R + 3) / 4), block(256);
        nerf_sample_pdf_generic<<<grid, block, 0, stream>>>(
            rays_o, rays_d, weights, bound_p, out, R, Tm1, n);
    }
}